// Round 12
// baseline (79.137 us; speedup 1.0000x reference)
//
#include <hip/hip_runtime.h>
#include <math.h>

// Problem constants
#define B_  2
#define S_  2048
#define D_  512
#define H_  8
#define DK_ 64
#define M_  (B_*S_)        // 4096
#define NW   (D_*D_)       // 262144 elems per weight

typedef __attribute__((ext_vector_type(8))) short bf16x8;
typedef __attribute__((ext_vector_type(4))) float f32x4;

__device__ inline unsigned short f2bf(float f) {
    union { float f; unsigned int u; } a; a.f = f;
    unsigned int u = a.u;
    u += 0x7FFFu + ((u >> 16) & 1u);   // RNE
    return (unsigned short)(u >> 16);
}

// async global->LDS, 16B per lane. LDS dest must be linear in lane id.
#define GLL(g, l) __builtin_amdgcn_global_load_lds( \
    (const __attribute__((address_space(1))) unsigned int*)(g), \
    (__attribute__((address_space(3))) unsigned int*)(l), 16, 0, 0)

__device__ inline void cvtw8(unsigned short* d, float4 v0, float4 v1) {
    union { bf16x8 v; unsigned short s[8]; } u;
    u.s[0]=f2bf(v0.x); u.s[1]=f2bf(v0.y); u.s[2]=f2bf(v0.z); u.s[3]=f2bf(v0.w);
    u.s[4]=f2bf(v1.x); u.s[5]=f2bf(v1.y); u.s[6]=f2bf(v1.z); u.s[7]=f2bf(v1.w);
    *(bf16x8*)d = u.v;
}

// ---------------------------------------------------------------------------
// Fused Q/K/V projection GEMM, tile 64x128 (M x N), BK=32, 4 waves (2x2,
// each wave 32x64). Both A (activations) and W fp32, reg-staged + converted
// in-kernel, dbuf LDS, 1 barrier/iter. Grid (192, 4): blockIdx.x =
// seg*64 + m-tile, seg 0/1/2 = q/k/v; blockIdx.y = n-tile (128 wide).
// A-conversion amortized over 4 n-blocks (was 8 at 64x64); 8 MFMA/barrier.
// seg 0: bf16 [B,H,S,DK] scaled 0.125. seg 1: [B,H,S,DK]. seg 2: [B,H,DK,S].
// ---------------------------------------------------------------------------
__global__ __launch_bounds__(256) void qkv_gemm(
    const float* __restrict__ qF, const float* __restrict__ kF,
    const float* __restrict__ vF,
    const float* __restrict__ Wq, const float* __restrict__ Wk,
    const float* __restrict__ Wv,
    const float* __restrict__ bq, const float* __restrict__ bk,
    const float* __restrict__ bv,
    unsigned short* __restrict__ q_ws, unsigned short* __restrict__ k_ws,
    unsigned short* __restrict__ vT_ws)
{
    __shared__ unsigned short A_lds[2][64][32];    // 64 rows x 32 k
    __shared__ unsigned short B_lds[2][128][32];   // 128 w-rows x 32 k

    const int t    = threadIdx.x;
    const int lane = t & 63;
    const int wave = t >> 6;
    const int wm   = wave >> 1, wn = wave & 1;     // 2x2 waves, 32x64 each
    const int lrow = lane & 15, lgr = lane >> 4;
    const int seg  = blockIdx.x >> 6;
    const int bm   = blockIdx.x & 63;
    const int bn   = blockIdx.y;

    const float*    A    = seg == 0 ? qF : seg == 1 ? kF : vF;
    const float*    W    = seg == 0 ? Wq : seg == 1 ? Wk : Wv;
    const float*    bias = seg == 0 ? bq : seg == 1 ? bk : bv;
    unsigned short* Cp   = seg == 0 ? q_ws : seg == 1 ? k_ws : vT_ws;

    f32x4 acc[2][4] = {};

    // A staging: 64x32 = 2048 shorts, 8/thread: row t>>2, cols (t&3)*8
    const float* Agp = A + (size_t)(bm*64 + (t>>2))*512 + (t&3)*8;
    // W staging: 128x32 = 4096 shorts, 16/thread: row t>>1, cols (t&1)*16
    const float* Wgp = W + (size_t)(bn*128 + (t>>1))*512 + (t&1)*16;
    unsigned short* lA0 = &A_lds[0][t>>2][(t&3)*8];
    unsigned short* lA1 = &A_lds[1][t>>2][(t&3)*8];
    unsigned short* lB0 = &B_lds[0][t>>1][(t&1)*16];
    unsigned short* lB1 = &B_lds[1][t>>1][(t&1)*16];

    // prologue: tile 0 staged to buf0, tile 1 loads in flight
    float4 a0n = *(const float4*)(Agp);
    float4 a1n = *(const float4*)(Agp + 4);
    float4 w0n = *(const float4*)(Wgp);
    float4 w1n = *(const float4*)(Wgp + 4);
    float4 w2n = *(const float4*)(Wgp + 8);
    float4 w3n = *(const float4*)(Wgp + 12);
    cvtw8(lA0, a0n, a1n);
    cvtw8(lB0,      w0n, w1n);
    cvtw8(lB0 + 8,  w2n, w3n);
    a0n = *(const float4*)(Agp + 32);
    a1n = *(const float4*)(Agp + 36);
    w0n = *(const float4*)(Wgp + 32);
    w1n = *(const float4*)(Wgp + 36);
    w2n = *(const float4*)(Wgp + 40);
    w3n = *(const float4*)(Wgp + 44);

    #pragma unroll
    for (int i = 0; i < 16; ++i) {
        __syncthreads();                         // tile i visible
        const int buf = i & 1;
        if (i < 15) {                            // stage tile i+1 -> buf^1
            cvtw8(buf ? lA0 : lA1, a0n, a1n);
            cvtw8((buf ? lB0 : lB1),     w0n, w1n);
            cvtw8((buf ? lB0 : lB1) + 8, w2n, w3n);
        }
        if (i < 14) {                            // issue tile i+2 loads
            a0n = *(const float4*)(Agp + (i+2)*32);
            a1n = *(const float4*)(Agp + (i+2)*32 + 4);
            w0n = *(const float4*)(Wgp + (i+2)*32);
            w1n = *(const float4*)(Wgp + (i+2)*32 + 4);
            w2n = *(const float4*)(Wgp + (i+2)*32 + 8);
            w3n = *(const float4*)(Wgp + (i+2)*32 + 12);
        }

        bf16x8 a0 = *(const bf16x8*)&A_lds[buf][wm*32 +      lrow][lgr*8];
        bf16x8 a1 = *(const bf16x8*)&A_lds[buf][wm*32 + 16 + lrow][lgr*8];
        bf16x8 b[4];
        #pragma unroll
        for (int nf = 0; nf < 4; ++nf)
            b[nf] = *(const bf16x8*)&B_lds[buf][wn*64 + nf*16 + lrow][lgr*8];

        #pragma unroll
        for (int nf = 0; nf < 4; ++nf) {
            acc[0][nf] = __builtin_amdgcn_mfma_f32_16x16x32_bf16(a0, b[nf], acc[0][nf], 0, 0, 0);
            acc[1][nf] = __builtin_amdgcn_mfma_f32_16x16x32_bf16(a1, b[nf], acc[1][nf], 0, 0, 0);
        }
    }

    #pragma unroll
    for (int mf = 0; mf < 2; ++mf)
    #pragma unroll
    for (int nf = 0; nf < 4; ++nf)
    #pragma unroll
    for (int r = 0; r < 4; ++r) {
        int grow = bm*64 + wm*32 + mf*16 + lgr*4 + r;
        int gcol = bn*128 + wn*64 + nf*16 + lrow;
        float v = acc[mf][nf][r] + bias[gcol];
        if (seg == 0) v *= 0.125f;   // 1/sqrt(DK) folded into Q
        int bb = grow >> 11, s = grow & 2047;
        int hh = gcol >> 6,  dk = gcol & 63;
        unsigned short bv16 = f2bf(v);
        if (seg < 2)
            Cp[((size_t)(bb*H_ + hh)*S_ + s)*DK_ + dk] = bv16;
        else
            Cp[((size_t)(bb*H_ + hh)*DK_ + dk)*S_ + s] = bv16;
    }
}

// ---------------------------------------------------------------------------
// Output projection: fp32 out = attn(bf16) @ Wo^T + bo.
// A via global_load_lds dbuf; Wo fp32 reg-staged + converted in-kernel.
// (64x64 tile: N=512 keeps grid at 512 blocks = 2/CU; wider tiles would
// drop to 1/CU.)
// ---------------------------------------------------------------------------
__global__ __launch_bounds__(256) void out_gemm(
    const unsigned short* __restrict__ A,
    const float* __restrict__ W,
    const float* __restrict__ bias,
    float* __restrict__ C)
{
    __shared__ unsigned short A_lds[2][64][32];
    __shared__ unsigned short B_lds[2][64][32];

    const int t    = threadIdx.x;
    const int lane = t & 63;
    const int wave = t >> 6;
    const int wm   = wave >> 1, wn = wave & 1;
    const int lrow = lane & 15, lgr = lane >> 4;
    const int bm   = blockIdx.x, bn = blockIdx.y;

    f32x4 acc[2][2] = {};

    const unsigned short* Ag = A + (size_t)(bm*64 + (t>>2))*512 + (t&3)*8;
    const float* Wgp = W + (size_t)(bn*64 + (t>>2))*512 + (t&3)*8;
    unsigned short* lA0 = &A_lds[0][t>>2][(t&3)*8];
    unsigned short* lA1 = &A_lds[1][t>>2][(t&3)*8];
    unsigned short* lB0 = &B_lds[0][t>>2][(t&3)*8];
    unsigned short* lB1 = &B_lds[1][t>>2][(t&3)*8];

    GLL(Ag, lA0);
    float4 w0n = *(const float4*)(Wgp);
    float4 w1n = *(const float4*)(Wgp + 4);
    cvtw8(lB0, w0n, w1n);
    w0n = *(const float4*)(Wgp + 32);
    w1n = *(const float4*)(Wgp + 36);

    #pragma unroll
    for (int i = 0; i < 16; ++i) {
        __syncthreads();
        const int buf = i & 1;
        if (i < 15) {
            GLL(Ag + (i+1)*32, buf ? lA0 : lA1);
            cvtw8(buf ? lB0 : lB1, w0n, w1n);
        }
        if (i < 14) {
            w0n = *(const float4*)(Wgp + (i+2)*32);
            w1n = *(const float4*)(Wgp + (i+2)*32 + 4);
        }

        bf16x8 a0 = *(const bf16x8*)&A_lds[buf][wm*32 +      lrow][lgr*8];
        bf16x8 a1 = *(const bf16x8*)&A_lds[buf][wm*32 + 16 + lrow][lgr*8];
        bf16x8 b0 = *(const bf16x8*)&B_lds[buf][wn*32 +      lrow][lgr*8];
        bf16x8 b1 = *(const bf16x8*)&B_lds[buf][wn*32 + 16 + lrow][lgr*8];

        acc[0][0] = __builtin_amdgcn_mfma_f32_16x16x32_bf16(a0, b0, acc[0][0], 0, 0, 0);
        acc[0][1] = __builtin_amdgcn_mfma_f32_16x16x32_bf16(a0, b1, acc[0][1], 0, 0, 0);
        acc[1][0] = __builtin_amdgcn_mfma_f32_16x16x32_bf16(a1, b0, acc[1][0], 0, 0, 0);
        acc[1][1] = __builtin_amdgcn_mfma_f32_16x16x32_bf16(a1, b1, acc[1][1], 0, 0, 0);
    }

    #pragma unroll
    for (int mf = 0; mf < 2; ++mf)
    #pragma unroll
    for (int nf = 0; nf < 2; ++nf)
    #pragma unroll
    for (int r = 0; r < 4; ++r) {
        int grow = bm*64 + wm*32 + mf*16 + lgr*4 + r;
        int gcol = bn*64 + wn*32 + nf*16 + lrow;
        C[(size_t)grow*512 + gcol] = acc[mf][nf][r] + bias[gcol];
    }
}

// ---------------------------------------------------------------------------
// Attention — FROZEN at the measured-best R3/R11 structure (48.5-48.7us):
// 8 waves (4 q-subtiles x 2 k-halves), pad-72 LDS, no-max softmax via __expf
// (Q pre-scaled 0.125), reg-staged K/V prefetch, per-wave P_lds, additive
// in-LDS merge of the two k-halves. No setprio.
// ---------------------------------------------------------------------------
__global__ __launch_bounds__(512, 4) void attn_fast(
    const unsigned short* __restrict__ q_ws,
    const unsigned short* __restrict__ k_ws,
    const unsigned short* __restrict__ vT_ws,
    const float* __restrict__ sph,
    unsigned short* __restrict__ attn_ws)
{
    __shared__ unsigned short K_lds[2][64][72];
    __shared__ unsigned short V_lds[2][64][72];
    __shared__ unsigned short P_lds[8][16][72];
    __shared__ float l_sh[8][16];
    // O_sh overlays K_lds (dead after main loop): 4*16*72*4 = 18432 = sizeof(K_lds)
    float (*O_sh)[16][72] = (float (*)[16][72])(&K_lds[0][0][0]);

    const int t    = threadIdx.x;
    const int lane = t & 63, wave = t >> 6;
    const int lrow = lane & 15, lgr = lane >> 4;
    const int wq = wave & 3;      // q sub-tile (16 rows)
    const int wh = wave >> 2;     // k half
    const int qt = blockIdx.x, bh = blockIdx.y;
    const int b  = bh >> 3;
    const int h  = bh & 7;
    const int qbase = qt * 64;
    const size_t head_off = (size_t)bh * S_ * DK_;

    bf16x8 qf0, qf1;
    {
        const unsigned short* qp =
            q_ws + head_off + (size_t)(qbase + wq*16 + lrow)*DK_ + lgr*8;
        qf0 = *(const bf16x8*)qp;
        qf1 = *(const bf16x8*)(qp + 32);
    }

    const int sh = t >> 8;
    const int sr = (t >> 2) & 63;
    const int sc = (t & 3) * 16;
    const unsigned short* kstage = k_ws  + head_off + ((size_t)sh*1024 + sr)*DK_ + sc;
    const unsigned short* vstage = vT_ws + head_off + (size_t)sr*S_ + sh*1024 + sc;

    const float* sphb   = sph + (size_t)b * S_ * S_;
    const float* sph_p0 = sphb + (size_t)(qbase + wq*16 + lgr*4 + 0)*S_ + wh*1024 + lrow;
    const float* sph_p1 = sph_p0 + S_;
    const float* sph_p2 = sph_p0 + 2*S_;
    const float* sph_p3 = sph_p0 + 3*S_;

    f32x4 acc_o[4] = {};
    float psum[4] = {0.f, 0.f, 0.f, 0.f};

    // prologue: stage tile 0 + sph tile 0
    bf16x8 kr0 = *(const bf16x8*)(kstage);
    bf16x8 kr1 = *(const bf16x8*)(kstage + 8);
    bf16x8 vr0 = *(const bf16x8*)(vstage);
    bf16x8 vr1 = *(const bf16x8*)(vstage + 8);
    *(bf16x8*)&K_lds[sh][sr][sc]     = kr0;
    *(bf16x8*)&K_lds[sh][sr][sc + 8] = kr1;
    *(bf16x8*)&V_lds[sh][sr][sc]     = vr0;
    *(bf16x8*)&V_lds[sh][sr][sc + 8] = vr1;

    float sphr[4][4];
    #pragma unroll
    for (int nf = 0; nf < 4; ++nf) {
        sphr[nf][0] = sph_p0[nf*16];
        sphr[nf][1] = sph_p1[nf*16];
        sphr[nf][2] = sph_p2[nf*16];
        sphr[nf][3] = sph_p3[nf*16];
    }

    for (int kt = 0; kt < 16; ++kt) {
        __syncthreads();   // LDS tile kt ready

        if (kt < 15) {     // next-tile K/V register prefetch
            const unsigned short* kp = kstage + (size_t)(kt+1)*64*DK_;
            const unsigned short* vp = vstage + (kt+1)*64;
            kr0 = *(const bf16x8*)(kp);
            kr1 = *(const bf16x8*)(kp + 8);
            vr0 = *(const bf16x8*)(vp);
            vr1 = *(const bf16x8*)(vp + 8);
        }

        // QK^T: 16 q rows x 64 k cols per wave
        f32x4 sc4[4];
        #pragma unroll
        for (int nf = 0; nf < 4; ++nf) {
            bf16x8 kf0 = *(const bf16x8*)&K_lds[wh][nf*16 + lrow][lgr*8];
            bf16x8 kf1 = *(const bf16x8*)&K_lds[wh][nf*16 + lrow][32 + lgr*8];
            f32x4 a = {};
            a = __builtin_amdgcn_mfma_f32_16x16x32_bf16(qf0, kf0, a, 0, 0, 0);
            a = __builtin_amdgcn_mfma_f32_16x16x32_bf16(qf1, kf1, a, 0, 0, 0);
            sc4[nf] = a;
        }

        // p = exp(score * sph); accumulate per-lane row-sum partials
        #pragma unroll
        for (int nf = 0; nf < 4; ++nf)
        #pragma unroll
        for (int r = 0; r < 4; ++r) {
            float p = __expf(sc4[nf][r] * sphr[nf][r]);
            sc4[nf][r] = p;
            psum[r] += p;
        }

        // P -> bf16 -> per-wave LDS (wave-private: no barrier needed)
        #pragma unroll
        for (int nf = 0; nf < 4; ++nf)
        #pragma unroll
        for (int r = 0; r < 4; ++r)
            P_lds[wave][lgr*4 + r][nf*16 + lrow] = f2bf(sc4[nf][r]);

        if (kt < 15) {     // next-tile sph prefetch (hides under PV)
            const int off = (kt + 1) * 64;
            #pragma unroll
            for (int nf = 0; nf < 4; ++nf) {
                sphr[nf][0] = sph_p0[off + nf*16];
                sphr[nf][1] = sph_p1[off + nf*16];
                sphr[nf][2] = sph_p2[off + nf*16];
                sphr[nf][3] = sph_p3[off + nf*16];
            }
        }

        // PV: acc_o[nb] += P @ V  (unnormalized accumulate)
        #pragma unroll
        for (int ks2 = 0; ks2 < 2; ++ks2) {
            bf16x8 pf = *(const bf16x8*)&P_lds[wave][lrow][ks2*32 + lgr*8];
            #pragma unroll
            for (int nb = 0; nb < 4; ++nb) {
                bf16x8 vf = *(const bf16x8*)&V_lds[wh][nb*16 + lrow][ks2*32 + lgr*8];
                acc_o[nb] = __builtin_amdgcn_mfma_f32_16x16x32_bf16(pf, vf, acc_o[nb], 0, 0, 0);
            }
        }
        __syncthreads();   // all K/V_lds reads done

        if (kt < 15) {
            *(bf16x8*)&K_lds[sh][sr][sc]     = kr0;
            *(bf16x8*)&K_lds[sh][sr][sc + 8] = kr1;
            *(bf16x8*)&V_lds[sh][sr][sc]     = vr0;
            *(bf16x8*)&V_lds[sh][sr][sc + 8] = vr1;
        }
    }

    // one-time row-sum reduce (over lrow lanes within each lgr group)
    #pragma unroll
    for (int off = 1; off < 16; off <<= 1)
        #pragma unroll
        for (int r = 0; r < 4; ++r)
            psum[r] += __shfl_xor(psum[r], off, 64);

    if (lrow == 0) {
        #pragma unroll
        for (int r = 0; r < 4; ++r)
            l_sh[wave][lgr*4 + r] = psum[r];
    }
    __syncthreads();

    float linv[4];
    #pragma unroll
    for (int r = 0; r < 4; ++r) {
        int row = lgr*4 + r;
        linv[r] = 1.f / (l_sh[wq][row] + l_sh[wq + 4][row]);
    }
    if (wh == 1) {
        #pragma unroll
        for (int nb = 0; nb < 4; ++nb)
        #pragma unroll
        for (int r = 0; r < 4; ++r)
            O_sh[wq][lgr*4 + r][nb*16 + lrow] = acc_o[nb][r];
    }
    __syncthreads();
    if (wh == 0) {
        #pragma unroll
        for (int nb = 0; nb < 4; ++nb)
        #pragma unroll
        for (int r = 0; r < 4; ++r) {
            int qrow = qbase + wq*16 + lgr*4 + r;
            float o = (acc_o[nb][r] + O_sh[wq][lgr*4 + r][nb*16 + lrow]) * linv[r];
            attn_ws[((size_t)(b*S_) + qrow)*D_ + h*64 + nb*16 + lrow] = f2bf(o);
        }
    }
}

// ---------------------------------------------------------------------------
extern "C" void kernel_launch(void* const* d_in, const int* in_sizes, int n_in,
                              void* d_out, int out_size, void* d_ws, size_t ws_size,
                              hipStream_t stream) {
    (void)in_sizes; (void)n_in; (void)out_size; (void)ws_size;
    const float* query = (const float*)d_in[0];
    const float* key_  = (const float*)d_in[1];
    const float* value = (const float*)d_in[2];
    const float* sph   = (const float*)d_in[3];
    const float* Wq = (const float*)d_in[4];
    const float* bq = (const float*)d_in[5];
    const float* Wk = (const float*)d_in[6];
    const float* bk = (const float*)d_in[7];
    const float* Wv = (const float*)d_in[8];
    const float* bv = (const float*)d_in[9];
    const float* Wo = (const float*)d_in[10];
    const float* bo = (const float*)d_in[11];

    char* ws = (char*)d_ws;
    const size_t MB = 1024*1024;

    // layout: [0 q_ws(4)][4 k_ws(4)][8 vT_ws(4)][12 attn_ws(4)] = 16MB
    unsigned short* q_ws    = (unsigned short*)(ws);
    unsigned short* k_ws    = (unsigned short*)(ws + 4*MB);
    unsigned short* vT_ws   = (unsigned short*)(ws + 8*MB);
    unsigned short* attn_ws = (unsigned short*)(ws + 12*MB);

    qkv_gemm<<<dim3(192, 4), 256, 0, stream>>>(query, key_, value, Wq, Wk, Wv,
                                               bq, bk, bv, q_ws, k_ws, vT_ws);
    attn_fast<<<dim3(S_/64, B_*H_), 512, 0, stream>>>(q_ws, k_ws, vT_ws, sph, attn_ws);
    out_gemm<<<dim3(64, 8), 256, 0, stream>>>(attn_ws, Wo, bo, (float*)d_out);
}

// Round 13
// 77.213 us; speedup vs baseline: 1.0249x; 1.0249x over previous
//
#include <hip/hip_runtime.h>
#include <math.h>

// Problem constants
#define B_  2
#define S_  2048
#define D_  512
#define H_  8
#define DK_ 64
#define M_  (B_*S_)        // 4096
#define NW   (D_*D_)       // 262144 elems per weight

typedef __attribute__((ext_vector_type(8))) short bf16x8;
typedef __attribute__((ext_vector_type(4))) float f32x4;

__device__ inline unsigned short f2bf(float f) {
    union { float f; unsigned int u; } a; a.f = f;
    unsigned int u = a.u;
    u += 0x7FFFu + ((u >> 16) & 1u);   // RNE
    return (unsigned short)(u >> 16);
}

// async global->LDS, 16B per lane. LDS dest must be linear in lane id.
#define GLL(g, l) __builtin_amdgcn_global_load_lds( \
    (const __attribute__((address_space(1))) unsigned int*)(g), \
    (__attribute__((address_space(3))) unsigned int*)(l), 16, 0, 0)

__device__ inline void cvtw8(unsigned short* d, float4 v0, float4 v1) {
    union { bf16x8 v; unsigned short s[8]; } u;
    u.s[0]=f2bf(v0.x); u.s[1]=f2bf(v0.y); u.s[2]=f2bf(v0.z); u.s[3]=f2bf(v0.w);
    u.s[4]=f2bf(v1.x); u.s[5]=f2bf(v1.y); u.s[6]=f2bf(v1.z); u.s[7]=f2bf(v1.w);
    *(bf16x8*)d = u.v;
}

// ---------------------------------------------------------------------------
// Fused Q/K/V projection GEMM (R11-proven, 64x64 tile). BOTH A and W fp32,
// reg-staged + converted in-kernel (2-deep pipe), dbuf LDS, 1 barrier/iter.
// Grid (192, 8): blockIdx.x = seg*64 + row-tile, seg 0/1/2 = q/k/v.
// ---------------------------------------------------------------------------
__global__ __launch_bounds__(256) void qkv_gemm(
    const float* __restrict__ qF, const float* __restrict__ kF,
    const float* __restrict__ vF,
    const float* __restrict__ Wq, const float* __restrict__ Wk,
    const float* __restrict__ Wv,
    const float* __restrict__ bq, const float* __restrict__ bk,
    const float* __restrict__ bv,
    unsigned short* __restrict__ q_ws, unsigned short* __restrict__ k_ws,
    unsigned short* __restrict__ vT_ws)
{
    __shared__ unsigned short A_lds[2][64][32];
    __shared__ unsigned short B_lds[2][64][32];

    const int t    = threadIdx.x;
    const int lane = t & 63;
    const int wave = t >> 6;
    const int wm   = wave >> 1, wn = wave & 1;
    const int lrow = lane & 15, lgr = lane >> 4;
    const int seg  = blockIdx.x >> 6;
    const int bm   = blockIdx.x & 63;
    const int bn   = blockIdx.y;

    const float*    A    = seg == 0 ? qF : seg == 1 ? kF : vF;
    const float*    W    = seg == 0 ? Wq : seg == 1 ? Wk : Wv;
    const float*    bias = seg == 0 ? bq : seg == 1 ? bk : bv;
    unsigned short* Cp   = seg == 0 ? q_ws : seg == 1 ? k_ws : vT_ws;

    f32x4 acc[2][2] = {};

    const float* Agp = A + (size_t)(bm*64 + (t>>2))*512 + (t&3)*8;
    const float* Wgp = W + (size_t)(bn*64 + (t>>2))*512 + (t&3)*8;
    unsigned short* lA0 = &A_lds[0][t>>2][(t&3)*8];
    unsigned short* lA1 = &A_lds[1][t>>2][(t&3)*8];
    unsigned short* lB0 = &B_lds[0][t>>2][(t&3)*8];
    unsigned short* lB1 = &B_lds[1][t>>2][(t&3)*8];

    // prologue: tile 0 staged to buf0, tile 1 loads in flight
    float4 a0n = *(const float4*)(Agp);
    float4 a1n = *(const float4*)(Agp + 4);
    float4 w0n = *(const float4*)(Wgp);
    float4 w1n = *(const float4*)(Wgp + 4);
    cvtw8(lA0, a0n, a1n);
    cvtw8(lB0, w0n, w1n);
    a0n = *(const float4*)(Agp + 32);
    a1n = *(const float4*)(Agp + 36);
    w0n = *(const float4*)(Wgp + 32);
    w1n = *(const float4*)(Wgp + 36);

    #pragma unroll
    for (int i = 0; i < 16; ++i) {
        __syncthreads();                         // tile i visible
        const int buf = i & 1;
        if (i < 15) {                            // stage tile i+1 -> buf^1
            cvtw8(buf ? lA0 : lA1, a0n, a1n);
            cvtw8(buf ? lB0 : lB1, w0n, w1n);
        }
        if (i < 14) {                            // issue tile i+2 loads
            a0n = *(const float4*)(Agp + (i+2)*32);
            a1n = *(const float4*)(Agp + (i+2)*32 + 4);
            w0n = *(const float4*)(Wgp + (i+2)*32);
            w1n = *(const float4*)(Wgp + (i+2)*32 + 4);
        }

        bf16x8 a0 = *(const bf16x8*)&A_lds[buf][wm*32 +      lrow][lgr*8];
        bf16x8 a1 = *(const bf16x8*)&A_lds[buf][wm*32 + 16 + lrow][lgr*8];
        bf16x8 b0 = *(const bf16x8*)&B_lds[buf][wn*32 +      lrow][lgr*8];
        bf16x8 b1 = *(const bf16x8*)&B_lds[buf][wn*32 + 16 + lrow][lgr*8];

        acc[0][0] = __builtin_amdgcn_mfma_f32_16x16x32_bf16(a0, b0, acc[0][0], 0, 0, 0);
        acc[0][1] = __builtin_amdgcn_mfma_f32_16x16x32_bf16(a0, b1, acc[0][1], 0, 0, 0);
        acc[1][0] = __builtin_amdgcn_mfma_f32_16x16x32_bf16(a1, b0, acc[1][0], 0, 0, 0);
        acc[1][1] = __builtin_amdgcn_mfma_f32_16x16x32_bf16(a1, b1, acc[1][1], 0, 0, 0);
    }

    #pragma unroll
    for (int mf = 0; mf < 2; ++mf)
    #pragma unroll
    for (int nf = 0; nf < 2; ++nf)
    #pragma unroll
    for (int r = 0; r < 4; ++r) {
        int grow = bm*64 + wm*32 + mf*16 + lgr*4 + r;
        int gcol = bn*64 + wn*32 + nf*16 + lrow;
        float v = acc[mf][nf][r] + bias[gcol];
        if (seg == 0) v *= 0.125f;   // 1/sqrt(DK) folded into Q
        int bb = grow >> 11, s = grow & 2047;
        int hh = gcol >> 6,  dk = gcol & 63;
        unsigned short bv16 = f2bf(v);
        if (seg < 2)
            Cp[((size_t)(bb*H_ + hh)*S_ + s)*DK_ + dk] = bv16;
        else
            Cp[((size_t)(bb*H_ + hh)*DK_ + dk)*S_ + s] = bv16;
    }
}

// ---------------------------------------------------------------------------
// Output projection: fp32 out = attn(bf16) @ Wo^T + bo.
// A via global_load_lds dbuf; Wo fp32 reg-staged + converted in-kernel.
// ---------------------------------------------------------------------------
__global__ __launch_bounds__(256) void out_gemm(
    const unsigned short* __restrict__ A,
    const float* __restrict__ W,
    const float* __restrict__ bias,
    float* __restrict__ C)
{
    __shared__ unsigned short A_lds[2][64][32];
    __shared__ unsigned short B_lds[2][64][32];

    const int t    = threadIdx.x;
    const int lane = t & 63;
    const int wave = t >> 6;
    const int wm   = wave >> 1, wn = wave & 1;
    const int lrow = lane & 15, lgr = lane >> 4;
    const int bm   = blockIdx.x, bn = blockIdx.y;

    f32x4 acc[2][2] = {};

    const unsigned short* Ag = A + (size_t)(bm*64 + (t>>2))*512 + (t&3)*8;
    const float* Wgp = W + (size_t)(bn*64 + (t>>2))*512 + (t&3)*8;
    unsigned short* lA0 = &A_lds[0][t>>2][(t&3)*8];
    unsigned short* lA1 = &A_lds[1][t>>2][(t&3)*8];
    unsigned short* lB0 = &B_lds[0][t>>2][(t&3)*8];
    unsigned short* lB1 = &B_lds[1][t>>2][(t&3)*8];

    GLL(Ag, lA0);
    float4 w0n = *(const float4*)(Wgp);
    float4 w1n = *(const float4*)(Wgp + 4);
    cvtw8(lB0, w0n, w1n);
    w0n = *(const float4*)(Wgp + 32);
    w1n = *(const float4*)(Wgp + 36);

    #pragma unroll
    for (int i = 0; i < 16; ++i) {
        __syncthreads();
        const int buf = i & 1;
        if (i < 15) {
            GLL(Ag + (i+1)*32, buf ? lA0 : lA1);
            cvtw8(buf ? lB0 : lB1, w0n, w1n);
        }
        if (i < 14) {
            w0n = *(const float4*)(Wgp + (i+2)*32);
            w1n = *(const float4*)(Wgp + (i+2)*32 + 4);
        }

        bf16x8 a0 = *(const bf16x8*)&A_lds[buf][wm*32 +      lrow][lgr*8];
        bf16x8 a1 = *(const bf16x8*)&A_lds[buf][wm*32 + 16 + lrow][lgr*8];
        bf16x8 b0 = *(const bf16x8*)&B_lds[buf][wn*32 +      lrow][lgr*8];
        bf16x8 b1 = *(const bf16x8*)&B_lds[buf][wn*32 + 16 + lrow][lgr*8];

        acc[0][0] = __builtin_amdgcn_mfma_f32_16x16x32_bf16(a0, b0, acc[0][0], 0, 0, 0);
        acc[0][1] = __builtin_amdgcn_mfma_f32_16x16x32_bf16(a0, b1, acc[0][1], 0, 0, 0);
        acc[1][0] = __builtin_amdgcn_mfma_f32_16x16x32_bf16(a1, b0, acc[1][0], 0, 0, 0);
        acc[1][1] = __builtin_amdgcn_mfma_f32_16x16x32_bf16(a1, b1, acc[1][1], 0, 0, 0);
    }

    #pragma unroll
    for (int mf = 0; mf < 2; ++mf)
    #pragma unroll
    for (int nf = 0; nf < 2; ++nf)
    #pragma unroll
    for (int r = 0; r < 4; ++r) {
        int grow = bm*64 + wm*32 + mf*16 + lgr*4 + r;
        int gcol = bn*64 + wn*32 + nf*16 + lrow;
        C[(size_t)grow*512 + gcol] = acc[mf][nf][r] + bias[gcol];
    }
}

// ---------------------------------------------------------------------------
// Attention — FROZEN at the measured-best structure (48.4-49.0us across
// R3/R11/R12): 8 waves (4 q-subtiles x 2 k-halves), pad-72 LDS, no-max
// softmax via __expf (Q pre-scaled 0.125), reg-staged K/V prefetch,
// per-wave P_lds, additive in-LDS merge of the two k-halves. No setprio.
// ---------------------------------------------------------------------------
__global__ __launch_bounds__(512, 4) void attn_fast(
    const unsigned short* __restrict__ q_ws,
    const unsigned short* __restrict__ k_ws,
    const unsigned short* __restrict__ vT_ws,
    const float* __restrict__ sph,
    unsigned short* __restrict__ attn_ws)
{
    __shared__ unsigned short K_lds[2][64][72];
    __shared__ unsigned short V_lds[2][64][72];
    __shared__ unsigned short P_lds[8][16][72];
    __shared__ float l_sh[8][16];
    // O_sh overlays K_lds (dead after main loop): 4*16*72*4 = 18432 = sizeof(K_lds)
    float (*O_sh)[16][72] = (float (*)[16][72])(&K_lds[0][0][0]);

    const int t    = threadIdx.x;
    const int lane = t & 63, wave = t >> 6;
    const int lrow = lane & 15, lgr = lane >> 4;
    const int wq = wave & 3;      // q sub-tile (16 rows)
    const int wh = wave >> 2;     // k half
    const int qt = blockIdx.x, bh = blockIdx.y;
    const int b  = bh >> 3;
    const int h  = bh & 7;
    const int qbase = qt * 64;
    const size_t head_off = (size_t)bh * S_ * DK_;

    bf16x8 qf0, qf1;
    {
        const unsigned short* qp =
            q_ws + head_off + (size_t)(qbase + wq*16 + lrow)*DK_ + lgr*8;
        qf0 = *(const bf16x8*)qp;
        qf1 = *(const bf16x8*)(qp + 32);
    }

    const int sh = t >> 8;
    const int sr = (t >> 2) & 63;
    const int sc = (t & 3) * 16;
    const unsigned short* kstage = k_ws  + head_off + ((size_t)sh*1024 + sr)*DK_ + sc;
    const unsigned short* vstage = vT_ws + head_off + (size_t)sr*S_ + sh*1024 + sc;

    const float* sphb   = sph + (size_t)b * S_ * S_;
    const float* sph_p0 = sphb + (size_t)(qbase + wq*16 + lgr*4 + 0)*S_ + wh*1024 + lrow;
    const float* sph_p1 = sph_p0 + S_;
    const float* sph_p2 = sph_p0 + 2*S_;
    const float* sph_p3 = sph_p0 + 3*S_;

    f32x4 acc_o[4] = {};
    float psum[4] = {0.f, 0.f, 0.f, 0.f};

    // prologue: stage tile 0 + sph tile 0
    bf16x8 kr0 = *(const bf16x8*)(kstage);
    bf16x8 kr1 = *(const bf16x8*)(kstage + 8);
    bf16x8 vr0 = *(const bf16x8*)(vstage);
    bf16x8 vr1 = *(const bf16x8*)(vstage + 8);
    *(bf16x8*)&K_lds[sh][sr][sc]     = kr0;
    *(bf16x8*)&K_lds[sh][sr][sc + 8] = kr1;
    *(bf16x8*)&V_lds[sh][sr][sc]     = vr0;
    *(bf16x8*)&V_lds[sh][sr][sc + 8] = vr1;

    float sphr[4][4];
    #pragma unroll
    for (int nf = 0; nf < 4; ++nf) {
        sphr[nf][0] = sph_p0[nf*16];
        sphr[nf][1] = sph_p1[nf*16];
        sphr[nf][2] = sph_p2[nf*16];
        sphr[nf][3] = sph_p3[nf*16];
    }

    for (int kt = 0; kt < 16; ++kt) {
        __syncthreads();   // LDS tile kt ready

        if (kt < 15) {     // next-tile K/V register prefetch
            const unsigned short* kp = kstage + (size_t)(kt+1)*64*DK_;
            const unsigned short* vp = vstage + (kt+1)*64;
            kr0 = *(const bf16x8*)(kp);
            kr1 = *(const bf16x8*)(kp + 8);
            vr0 = *(const bf16x8*)(vp);
            vr1 = *(const bf16x8*)(vp + 8);
        }

        // QK^T: 16 q rows x 64 k cols per wave
        f32x4 sc4[4];
        #pragma unroll
        for (int nf = 0; nf < 4; ++nf) {
            bf16x8 kf0 = *(const bf16x8*)&K_lds[wh][nf*16 + lrow][lgr*8];
            bf16x8 kf1 = *(const bf16x8*)&K_lds[wh][nf*16 + lrow][32 + lgr*8];
            f32x4 a = {};
            a = __builtin_amdgcn_mfma_f32_16x16x32_bf16(qf0, kf0, a, 0, 0, 0);
            a = __builtin_amdgcn_mfma_f32_16x16x32_bf16(qf1, kf1, a, 0, 0, 0);
            sc4[nf] = a;
        }

        // p = exp(score * sph); accumulate per-lane row-sum partials
        #pragma unroll
        for (int nf = 0; nf < 4; ++nf)
        #pragma unroll
        for (int r = 0; r < 4; ++r) {
            float p = __expf(sc4[nf][r] * sphr[nf][r]);
            sc4[nf][r] = p;
            psum[r] += p;
        }

        // P -> bf16 -> per-wave LDS (wave-private: no barrier needed)
        #pragma unroll
        for (int nf = 0; nf < 4; ++nf)
        #pragma unroll
        for (int r = 0; r < 4; ++r)
            P_lds[wave][lgr*4 + r][nf*16 + lrow] = f2bf(sc4[nf][r]);

        if (kt < 15) {     // next-tile sph prefetch (hides under PV)
            const int off = (kt + 1) * 64;
            #pragma unroll
            for (int nf = 0; nf < 4; ++nf) {
                sphr[nf][0] = sph_p0[off + nf*16];
                sphr[nf][1] = sph_p1[off + nf*16];
                sphr[nf][2] = sph_p2[off + nf*16];
                sphr[nf][3] = sph_p3[off + nf*16];
            }
        }

        // PV: acc_o[nb] += P @ V  (unnormalized accumulate)
        #pragma unroll
        for (int ks2 = 0; ks2 < 2; ++ks2) {
            bf16x8 pf = *(const bf16x8*)&P_lds[wave][lrow][ks2*32 + lgr*8];
            #pragma unroll
            for (int nb = 0; nb < 4; ++nb) {
                bf16x8 vf = *(const bf16x8*)&V_lds[wh][nb*16 + lrow][ks2*32 + lgr*8];
                acc_o[nb] = __builtin_amdgcn_mfma_f32_16x16x32_bf16(pf, vf, acc_o[nb], 0, 0, 0);
            }
        }
        __syncthreads();   // all K/V_lds reads done

        if (kt < 15) {
            *(bf16x8*)&K_lds[sh][sr][sc]     = kr0;
            *(bf16x8*)&K_lds[sh][sr][sc + 8] = kr1;
            *(bf16x8*)&V_lds[sh][sr][sc]     = vr0;
            *(bf16x8*)&V_lds[sh][sr][sc + 8] = vr1;
        }
    }

    // one-time row-sum reduce (over lrow lanes within each lgr group)
    #pragma unroll
    for (int off = 1; off < 16; off <<= 1)
        #pragma unroll
        for (int r = 0; r < 4; ++r)
            psum[r] += __shfl_xor(psum[r], off, 64);

    if (lrow == 0) {
        #pragma unroll
        for (int r = 0; r < 4; ++r)
            l_sh[wave][lgr*4 + r] = psum[r];
    }
    __syncthreads();

    float linv[4];
    #pragma unroll
    for (int r = 0; r < 4; ++r) {
        int row = lgr*4 + r;
        linv[r] = 1.f / (l_sh[wq][row] + l_sh[wq + 4][row]);
    }
    if (wh == 1) {
        #pragma unroll
        for (int nb = 0; nb < 4; ++nb)
        #pragma unroll
        for (int r = 0; r < 4; ++r)
            O_sh[wq][lgr*4 + r][nb*16 + lrow] = acc_o[nb][r];
    }
    __syncthreads();
    if (wh == 0) {
        #pragma unroll
        for (int nb = 0; nb < 4; ++nb)
        #pragma unroll
        for (int r = 0; r < 4; ++r) {
            int qrow = qbase + wq*16 + lgr*4 + r;
            float o = (acc_o[nb][r] + O_sh[wq][lgr*4 + r][nb*16 + lrow]) * linv[r];
            attn_ws[((size_t)(b*S_) + qrow)*D_ + h*64 + nb*16 + lrow] = f2bf(o);
        }
    }
}

// ---------------------------------------------------------------------------
extern "C" void kernel_launch(void* const* d_in, const int* in_sizes, int n_in,
                              void* d_out, int out_size, void* d_ws, size_t ws_size,
                              hipStream_t stream) {
    (void)in_sizes; (void)n_in; (void)out_size; (void)ws_size;
    const float* query = (const float*)d_in[0];
    const float* key_  = (const float*)d_in[1];
    const float* value = (const float*)d_in[2];
    const float* sph   = (const float*)d_in[3];
    const float* Wq = (const float*)d_in[4];
    const float* bq = (const float*)d_in[5];
    const float* Wk = (const float*)d_in[6];
    const float* bk = (const float*)d_in[7];
    const float* Wv = (const float*)d_in[8];
    const float* bv = (const float*)d_in[9];
    const float* Wo = (const float*)d_in[10];
    const float* bo = (const float*)d_in[11];

    char* ws = (char*)d_ws;
    const size_t MB = 1024*1024;

    // layout: [0 q_ws(4)][4 k_ws(4)][8 vT_ws(4)][12 attn_ws(4)] = 16MB
    unsigned short* q_ws    = (unsigned short*)(ws);
    unsigned short* k_ws    = (unsigned short*)(ws + 4*MB);
    unsigned short* vT_ws   = (unsigned short*)(ws + 8*MB);
    unsigned short* attn_ws = (unsigned short*)(ws + 12*MB);

    qkv_gemm<<<dim3(192, 8), 256, 0, stream>>>(query, key_, value, Wq, Wk, Wv,
                                               bq, bk, bv, q_ws, k_ws, vT_ws);
    attn_fast<<<dim3(S_/64, B_*H_), 512, 0, stream>>>(q_ws, k_ws, vT_ws, sph, attn_ws);
    out_gemm<<<dim3(64, 8), 256, 0, stream>>>(attn_ws, Wo, bo, (float*)d_out);
}